// Round 1
// baseline (265.275 us; speedup 1.0000x reference)
//
#include <hip/hip_runtime.h>

#define EXPC 0.25505654442163f  // (1/sqrt(32)) * log2(e)

typedef __attribute__((ext_vector_type(8))) short bfrag;   // 8 bf16
typedef __attribute__((ext_vector_type(4))) float ffrag;   // 4 f32 acc
typedef __attribute__((ext_vector_type(8))) unsigned int u8v;
typedef __attribute__((ext_vector_type(4))) unsigned int u4v;
typedef __attribute__((ext_vector_type(2))) unsigned int u2v;

__device__ __forceinline__ short f2bf(float x) {
  union { float f; unsigned u; } v; v.f = x;
  return (short)((v.u + 0x8000u) >> 16);  // round-half-up
}

__device__ __forceinline__ unsigned int packbf(float a, float b) {
  return __builtin_amdgcn_perm(__float_as_uint(b) + 0x8000u,
                               __float_as_uint(a) + 0x8000u, 0x07060302u);
}

__device__ __forceinline__ bfrag cvtp(u8v x) {
  u4v r;
#pragma unroll
  for (int i = 0; i < 4; ++i)
    r[i] = __builtin_amdgcn_perm(x[2 * i + 1] + 0x8000u, x[2 * i] + 0x8000u, 0x07060302u);
  union { u4v u; bfrag b; } c; c.u = r; return c.b;
}
__device__ __forceinline__ bfrag cvt8(const float* __restrict__ p) {
  return cvtp(*(const u8v*)p);
}

// ---- fused K+V projection v2 (verbatim from R10) ----
__global__ __launch_bounds__(256, 4) void proj_kv(
    const float* __restrict__ kin, const float* __restrict__ Wk,
    const float* __restrict__ bk, const float* __restrict__ vin,
    const float* __restrict__ Wv, const float* __restrict__ bv,
    short* __restrict__ ko, short* __restrict__ vt) {
  const int t = threadIdx.x;
  const int lane = t & 63, wid = t >> 6;
  const int lrow = lane & 15, lq = lane >> 4;
  __shared__ __align__(16) char lds[18432];
  const int row4 = t >> 2, c4 = (t & 3) * 8;

  const bool isK = blockIdx.x < 512;
  if (isK) {
    const int bx = blockIdx.x >> 1, d0 = (blockIdx.x & 1) * 128;
    const int m0 = bx * 64;
    short* Ab = (short*)lds;
    short* Bb = (short*)(lds + 5120);
    short* tile = (short*)lds;
    ffrag acc[4][2] = {};
    u8v pa, pb0, pb1;
    pa  = *(const u8v*)(kin + (size_t)(m0 + row4) * 256 + c4);
    pb0 = *(const u8v*)(Wk + (size_t)(d0 + row4) * 256 + c4);
    pb1 = *(const u8v*)(Wk + (size_t)(d0 + 64 + row4) * 256 + c4);
    *(bfrag*)(Ab + row4 * 40 + c4) = cvtp(pa);
    *(bfrag*)(Bb + row4 * 40 + c4) = cvtp(pb0);
    *(bfrag*)(Bb + (64 + row4) * 40 + c4) = cvtp(pb1);
#pragma unroll 1
    for (int s = 0; s < 8; ++s) {
      __syncthreads();
      if (s < 7) {
        const int k1 = (s + 1) * 32;
        pa  = *(const u8v*)(kin + (size_t)(m0 + row4) * 256 + k1 + c4);
        pb0 = *(const u8v*)(Wk + (size_t)(d0 + row4) * 256 + k1 + c4);
        pb1 = *(const u8v*)(Wk + (size_t)(d0 + 64 + row4) * 256 + k1 + c4);
      }
      bfrag a[4], b[2];
#pragma unroll
      for (int i = 0; i < 4; ++i)
        a[i] = *(const bfrag*)(Ab + (i * 16 + lrow) * 40 + lq * 8);
#pragma unroll
      for (int j = 0; j < 2; ++j)
        b[j] = *(const bfrag*)(Bb + (wid * 32 + j * 16 + lrow) * 40 + lq * 8);
#pragma unroll
      for (int i = 0; i < 4; ++i)
#pragma unroll
        for (int j = 0; j < 2; ++j)
          acc[i][j] = __builtin_amdgcn_mfma_f32_16x16x32_bf16(a[i], b[j], acc[i][j], 0, 0, 0);
      __syncthreads();
      if (s < 7) {
        *(bfrag*)(Ab + row4 * 40 + c4) = cvtp(pa);
        *(bfrag*)(Bb + row4 * 40 + c4) = cvtp(pb0);
        *(bfrag*)(Bb + (64 + row4) * 40 + c4) = cvtp(pb1);
      }
    }
    __syncthreads();
#pragma unroll
    for (int j = 0; j < 2; ++j) {
      int dl = wid * 32 + j * 16 + lrow;
      float bs = bk[d0 + dl];
#pragma unroll
      for (int i = 0; i < 4; ++i)
#pragma unroll
        for (int r = 0; r < 4; ++r)
          tile[(i * 16 + lq * 4 + r) * 136 + dl] = f2bf(acc[i][j][r] + bs);
    }
    __syncthreads();
#pragma unroll
    for (int p = 0; p < 4; ++p) {
      int id2 = p * 256 + t;
      int row = id2 >> 4, c = id2 & 15;
      bfrag v = *(const bfrag*)(tile + row * 136 + c * 8);
      *(bfrag*)(ko + (size_t)(m0 + row) * 256 + d0 + c * 8) = v;
    }
  } else {
    const int t2 = blockIdx.x - 512;
    const int bx = t2 >> 1, d0 = (t2 & 1) * 128;
    const int n0 = bx * 64;
    short* Aw = (short*)lds;
    short* Bv = (short*)(lds + 10240);
    short* tile = (short*)lds;
    ffrag acc[2][4] = {};
    u8v pv, pw0, pw1;
    pw0 = *(const u8v*)(Wv + (size_t)(d0 + row4) * 256 + c4);
    pw1 = *(const u8v*)(Wv + (size_t)(d0 + 64 + row4) * 256 + c4);
    pv  = *(const u8v*)(vin + (size_t)(n0 + row4) * 256 + c4);
    *(bfrag*)(Aw + row4 * 40 + c4) = cvtp(pw0);
    *(bfrag*)(Aw + (64 + row4) * 40 + c4) = cvtp(pw1);
    *(bfrag*)(Bv + row4 * 40 + c4) = cvtp(pv);
#pragma unroll 1
    for (int s = 0; s < 8; ++s) {
      __syncthreads();
      if (s < 7) {
        const int k1 = (s + 1) * 32;
        pw0 = *(const u8v*)(Wv + (size_t)(d0 + row4) * 256 + k1 + c4);
        pw1 = *(const u8v*)(Wv + (size_t)(d0 + 64 + row4) * 256 + k1 + c4);
        pv  = *(const u8v*)(vin + (size_t)(n0 + row4) * 256 + k1 + c4);
      }
      bfrag a[2], b[4];
#pragma unroll
      for (int i = 0; i < 2; ++i)
        a[i] = *(const bfrag*)(Aw + (wid * 32 + i * 16 + lrow) * 40 + lq * 8);
#pragma unroll
      for (int j = 0; j < 4; ++j)
        b[j] = *(const bfrag*)(Bv + (j * 16 + lrow) * 40 + lq * 8);
#pragma unroll
      for (int i = 0; i < 2; ++i)
#pragma unroll
        for (int j = 0; j < 4; ++j)
          acc[i][j] = __builtin_amdgcn_mfma_f32_16x16x32_bf16(a[i], b[j], acc[i][j], 0, 0, 0);
      __syncthreads();
      if (s < 7) {
        *(bfrag*)(Aw + row4 * 40 + c4) = cvtp(pw0);
        *(bfrag*)(Aw + (64 + row4) * 40 + c4) = cvtp(pw1);
        *(bfrag*)(Bv + row4 * 40 + c4) = cvtp(pv);
      }
    }
    __syncthreads();
#pragma unroll
    for (int i = 0; i < 2; ++i)
#pragma unroll
      for (int r = 0; r < 4; ++r) {
        int dl = wid * 32 + i * 16 + lq * 4 + r;
        float bs = bv[d0 + dl];
#pragma unroll
        for (int j = 0; j < 4; ++j)
          tile[dl * 72 + j * 16 + lrow] = f2bf(acc[i][j][r] + bs);
      }
    __syncthreads();
    const int bt = n0 >> 10, sl0 = n0 & 1023;
#pragma unroll
    for (int p = 0; p < 4; ++p) {
      int id2 = p * 256 + t;
      int dl = id2 >> 3, c = id2 & 7;
      bfrag v = *(const bfrag*)(tile + dl * 72 + c * 8);
      *(bfrag*)(vt + (size_t)bt * 262144 + (size_t)(d0 + dl) * 1024 + sl0 + c * 8) = v;
    }
  }
}

// ---- fused attn v4: g-split grid (bt,qt,g) -> 1024 blocks x 512 thr ----
// Each block: 16 q-rows (half tile), 8 waves = 8 heads. av prefetched 1 chunk
// ahead; per-wave serial chain and register state halved vs v3.
__global__ __launch_bounds__(512, 4) void attn_fused(
    const float* __restrict__ query, const float* __restrict__ Wq,
    const float* __restrict__ bq, const float* __restrict__ Wo,
    const float* __restrict__ bo, const short* __restrict__ K,
    const short* __restrict__ Vt, const int* __restrict__ mask,
    float* __restrict__ out) {
  const int lane = threadIdx.x & 63, wid = threadIdx.x >> 6;  // wid = head
  const int lrow = lane & 15, lq = lane >> 4;
  const int id = blockIdx.x;                    // 1024 blocks
  const int qt = id >> 5;                       // 0..31
  const int bt = (((id >> 1) & 15) + (id >> 9)) & 15;  // swizzle: varies L per CU-pair
  const int g = id & 1;                         // row-half within 32-row tile
  const int q0 = qt * 32;
  const int L = mask[bt];
  const int h = wid;
  const bool isLast = (qt == 31);
  const int nvalid = min(max(L - q0, 0), 32);
  const int gn = nvalid - g * 16;               // valid rows in this half (<=16)

  if (gn <= 0 && !isLast) return;               // covered by qt=31 broadcast
  const bool dmode = isLast && (nvalid <= 0);   // whole tile invalid -> broadcast
  if (dmode && g == 1) return;                  // g=0 block handles broadcast alone
  const bool skip12 = isLast && (gn <= 0);      // all-invalid half: colsum only

  __shared__ __align__(16) short qx[16 * 264];               // 16-row X tile
  __shared__ __align__(16) unsigned int ptbuf[8][16 * 36];   // per-wave P^T
  unsigned int* ptg = &ptbuf[wid][0];
  float* vbuf = (float*)&ptbuf[0][0];                        // D-mode broadcast vec

  const short* Vb = Vt + ((size_t)bt * 8 + h) * 32768;  // [32][1024]
  float l_i;
  ffrag o[2] = {};  // o[dj]

  if (!skip12) {
    // ---- phase 1: Q projection (this half's 16 rows), pre-scaled by EXPC ----
    {
      const int n0 = h * 32;
      const float* X = query + ((size_t)bt * 1024 + q0 + g * 16) * 256;
      ffrag acc[2] = {};
      u8v xa, wb[2], xa_n, wb_n[2];
      xa = *(const u8v*)(X + (size_t)lrow * 256 + lq * 8);
#pragma unroll
      for (int j = 0; j < 2; ++j)
        wb[j] = *(const u8v*)(Wq + (size_t)(n0 + j * 16 + lrow) * 256 + lq * 8);
#pragma unroll 1
      for (int tt = 0; tt < 8; ++tt) {
        if (tt < 7) {
          const int kk = (tt + 1) * 32;
          xa_n = *(const u8v*)(X + (size_t)lrow * 256 + kk + lq * 8);
#pragma unroll
          for (int j = 0; j < 2; ++j)
            wb_n[j] = *(const u8v*)(Wq + (size_t)(n0 + j * 16 + lrow) * 256 + kk + lq * 8);
        }
        bfrag a = cvtp(xa);
#pragma unroll
        for (int j = 0; j < 2; ++j) {
          bfrag b = cvtp(wb[j]);
          acc[j] = __builtin_amdgcn_mfma_f32_16x16x32_bf16(a, b, acc[j], 0, 0, 0);
        }
        xa = xa_n;
#pragma unroll
        for (int j = 0; j < 2; ++j) wb[j] = wb_n[j];
      }
#pragma unroll
      for (int j = 0; j < 2; ++j) {
        int d = n0 + j * 16 + lrow;
        float bs = bq[d];
#pragma unroll
        for (int r = 0; r < 4; ++r)
          qx[(lq * 4 + r) * 264 + d] = f2bf((acc[j][r] + bs) * EXPC);
      }
    }
    // no barrier: wave reads only its own rows/cols until after write-x

    // ---- phase 2: S^T = K.Q^T; kf AND av prefetched one chunk ahead ----
    const short* Kb = K + (size_t)bt * 262144;  // [1024][256]
    bfrag qf = *(const bfrag*)(qx + lrow * 264 + h * 32 + lq * 8);
    const int nchunk = (L + 63) >> 6;
    float l_loc = 0.f;
    bfrag kf[4], kf_n[4], av[2][2], av_n[2][2];
#pragma unroll
    for (int f = 0; f < 4; ++f)
      kf[f] = *(const bfrag*)(Kb + (size_t)(f * 16 + lrow) * 256 + h * 32 + lq * 8);
#pragma unroll
    for (int dj = 0; dj < 2; ++dj)
#pragma unroll
      for (int b = 0; b < 2; ++b)
        av[dj][b] = *(const bfrag*)(Vb + (size_t)(dj * 16 + lrow) * 1024 + b * 32 + lq * 8);

#pragma unroll 1
    for (int c = 0; c < nchunk; ++c) {
      const int kc = c * 64;
      const ffrag zf = {0.f, 0.f, 0.f, 0.f};
      if (c + 1 < nchunk) {
#pragma unroll
        for (int f = 0; f < 4; ++f)
          kf_n[f] = *(const bfrag*)(Kb + (size_t)(kc + 64 + f * 16 + lrow) * 256 + h * 32 + lq * 8);
#pragma unroll
        for (int dj = 0; dj < 2; ++dj)
#pragma unroll
          for (int b = 0; b < 2; ++b)
            av_n[dj][b] = *(const bfrag*)(Vb + (size_t)(dj * 16 + lrow) * 1024 + kc + 64 + b * 32 + lq * 8);
      }
      ffrag st[4];
#pragma unroll
      for (int f = 0; f < 4; ++f)
        st[f] = __builtin_amdgcn_mfma_f32_16x16x32_bf16(kf[f], qf, zf, 0, 0, 0);

      float p[4][4];
      const bool fullc = (kc + 64 <= L);
      if (fullc) {
#pragma unroll
        for (int f = 0; f < 4; ++f)
#pragma unroll
          for (int r = 0; r < 4; ++r) {
            p[f][r] = __builtin_amdgcn_exp2f(st[f][r]);
            l_loc += p[f][r];
          }
      } else {
#pragma unroll
        for (int f = 0; f < 4; ++f)
#pragma unroll
          for (int r = 0; r < 4; ++r) {
            int kr = kc + f * 16 + lq * 4 + r;
            float pv = (kr < L) ? __builtin_amdgcn_exp2f(st[f][r]) : 0.f;
            p[f][r] = pv;
            l_loc += pv;
          }
      }
#pragma unroll
      for (int f = 0; f < 4; ++f) {
        u2v w;
        w[0] = packbf(p[f][0], p[f][1]);
        w[1] = packbf(p[f][2], p[f][3]);
        *(u2v*)(ptg + lrow * 36 + 8 * f + 2 * lq) = w;
      }
#pragma unroll
      for (int b = 0; b < 2; ++b) {
        u4v pv = *(const u4v*)(ptg + lrow * 36 + 16 * b + 4 * lq);
        union { u4v u; bfrag bf; } pt; pt.u = pv;
#pragma unroll
        for (int dj = 0; dj < 2; ++dj)
          o[dj] = __builtin_amdgcn_mfma_f32_16x16x32_bf16(av[dj][b], pt.bf, o[dj], 0, 0, 0);
      }
#pragma unroll
      for (int f = 0; f < 4; ++f) kf[f] = kf_n[f];
#pragma unroll
      for (int dj = 0; dj < 2; ++dj)
#pragma unroll
        for (int b = 0; b < 2; ++b) av[dj][b] = av_n[dj][b];
    }

    // row-sum l across the 4 lane-quads
    {
      float rs = l_loc;
      rs += __shfl_xor(rs, 16);
      rs += __shfl_xor(rs, 32);
      l_i = rs;
    }
  } else {
    l_i = 1024.f;
  }

  // ---- tail (qt=31 only): invalid rows -> colsum(V) via indicator MFMA ----
  if (isLast && gn < 16) {
    const bool inv = (lrow >= gn);  // gn<=0 -> all rows invalid
    if (inv) {
      l_i = 1024.f;
#pragma unroll
      for (int dj = 0; dj < 2; ++dj)
#pragma unroll
        for (int r = 0; r < 4; ++r) o[dj][r] = 0.f;
    }
    bfrag ind;
    {
      short iv = inv ? (short)0x3F80 : (short)0;
#pragma unroll
      for (int j = 0; j < 8; ++j) ind[j] = iv;
    }
#pragma unroll 2
    for (int kc = 0; kc < 1024; kc += 64) {
#pragma unroll
      for (int dj = 0; dj < 2; ++dj)
#pragma unroll
        for (int b = 0; b < 2; ++b) {
          bfrag avt = *(const bfrag*)(Vb + (size_t)(dj * 16 + lrow) * 1024 + kc + b * 32 + lq * 8);
          o[dj] = __builtin_amdgcn_mfma_f32_16x16x32_bf16(avt, ind, o[dj], 0, 0, 0);
        }
    }
  }

  // write x into qx: lane holds qrow(local) = lrow, d = h*32 + dj*16 + 4*lq + r
  {
    const float rcp = 1.0f / l_i;
#pragma unroll
    for (int dj = 0; dj < 2; ++dj) {
      u2v w;
      w[0] = packbf(o[dj][0] * rcp, o[dj][1] * rcp);
      w[1] = packbf(o[dj][2] * rcp, o[dj][3] * rcp);
      *(u2v*)(qx + lrow * 264 + h * 32 + dj * 16 + lq * 4) = w;
    }
  }
  __syncthreads();

  // ---- phase 3: output projection; Wo prefetched one slab ahead ----
  {
    const int n0 = h * 32;
    ffrag acc[2] = {};
    u8v wb[2], wb_n[2];
#pragma unroll
    for (int j = 0; j < 2; ++j)
      wb[j] = *(const u8v*)(Wo + (size_t)(n0 + j * 16 + lrow) * 256 + lq * 8);
#pragma unroll 1
    for (int tt = 0; tt < 8; ++tt) {
      const int k0 = tt * 32;
      if (tt < 7) {
#pragma unroll
        for (int j = 0; j < 2; ++j)
          wb_n[j] = *(const u8v*)(Wo + (size_t)(n0 + j * 16 + lrow) * 256 + k0 + 32 + lq * 8);
      }
      bfrag a = *(const bfrag*)(qx + lrow * 264 + k0 + lq * 8);
#pragma unroll
      for (int j = 0; j < 2; ++j) {
        bfrag b = cvtp(wb[j]);
        acc[j] = __builtin_amdgcn_mfma_f32_16x16x32_bf16(a, b, acc[j], 0, 0, 0);
      }
#pragma unroll
      for (int j = 0; j < 2; ++j) wb[j] = wb_n[j];
    }

    if (!dmode) {
      // normal store; partial blocks store only rows < L (qt=31 stores all)
#pragma unroll
      for (int j = 0; j < 2; ++j) {
        int d = n0 + j * 16 + lrow;
        float bs = bo[d];
#pragma unroll
        for (int r = 0; r < 4; ++r) {
          int qr = q0 + g * 16 + lq * 4 + r;
          if (qr < L || isLast)
            out[((size_t)bt * 1024 + qr) * 256 + d] = acc[j][r] + bs;
        }
      }
    } else {
      // D-mode: all rows identical -> build 256-vector in LDS, broadcast L..1023
      if (lq == 0) {
#pragma unroll
        for (int j = 0; j < 2; ++j) {
          int d = n0 + j * 16 + lrow;
          vbuf[d] = acc[j][0] + bo[d];
        }
      }
      __syncthreads();
      const int d = threadIdx.x & 255;
      const float vv = vbuf[d];
      float* ob = out + (size_t)bt * 1024 * 256 + d;
#pragma unroll 1
      for (int row = L + (threadIdx.x >> 8); row < 1024; row += 2)
        ob[(size_t)row * 256] = vv;
    }
  }
}

extern "C" void kernel_launch(void* const* d_in, const int* in_sizes, int n_in,
                              void* d_out, int out_size, void* d_ws, size_t ws_size,
                              hipStream_t stream) {
  const float* query = (const float*)d_in[0];
  const float* key   = (const float*)d_in[1];
  const float* value = (const float*)d_in[2];
  const int*   mask  = (const int*)d_in[3];
  const float* Wq = (const float*)d_in[4];
  const float* bq = (const float*)d_in[5];
  const float* Wk = (const float*)d_in[6];
  const float* bk = (const float*)d_in[7];
  const float* Wv = (const float*)d_in[8];
  const float* bv = (const float*)d_in[9];
  const float* Wo = (const float*)d_in[10];
  const float* bo = (const float*)d_in[11];
  float* out = (float*)d_out;

  // workspace: K bf16 (8 MB) + Vt bf16 (8 MB) = 16,777,216 bytes exactly
  short* k_ws  = (short*)d_ws;
  short* vt_ws = k_ws + 4194304;

  proj_kv<<<dim3(1024), 256, 0, stream>>>(key, Wk, bk, value, Wv, bv, k_ws, vt_ws);
  attn_fused<<<dim3(1024), 512, 0, stream>>>(query, Wq, bq, Wo, bo,
                                             k_ws, vt_ws, mask, out);
}

// Round 3
// 207.581 us; speedup vs baseline: 1.2779x; 1.2779x over previous
//
#include <hip/hip_runtime.h>

#define EXPC 0.25505654442163f  // (1/sqrt(32)) * log2(e)

typedef __attribute__((ext_vector_type(8))) short bfrag;   // 8 bf16
typedef __attribute__((ext_vector_type(4))) float ffrag;   // 4 f32 acc
typedef __attribute__((ext_vector_type(8))) unsigned int u8v;
typedef __attribute__((ext_vector_type(4))) unsigned int u4v;
typedef __attribute__((ext_vector_type(2))) unsigned int u2v;

__device__ __forceinline__ short f2bf(float x) {
  union { float f; unsigned u; } v; v.f = x;
  return (short)((v.u + 0x8000u) >> 16);  // round-half-up
}

__device__ __forceinline__ unsigned int packbf(float a, float b) {
  return __builtin_amdgcn_perm(__float_as_uint(b) + 0x8000u,
                               __float_as_uint(a) + 0x8000u, 0x07060302u);
}

__device__ __forceinline__ bfrag cvtp(u8v x) {
  u4v r;
#pragma unroll
  for (int i = 0; i < 4; ++i)
    r[i] = __builtin_amdgcn_perm(x[2 * i + 1] + 0x8000u, x[2 * i] + 0x8000u, 0x07060302u);
  union { u4v u; bfrag b; } c; c.u = r; return c.b;
}

// ---- fused K+V projection v2 (verbatim) ----
__global__ __launch_bounds__(256, 4) void proj_kv(
    const float* __restrict__ kin, const float* __restrict__ Wk,
    const float* __restrict__ bk, const float* __restrict__ vin,
    const float* __restrict__ Wv, const float* __restrict__ bv,
    short* __restrict__ ko, short* __restrict__ vt) {
  const int t = threadIdx.x;
  const int lane = t & 63, wid = t >> 6;
  const int lrow = lane & 15, lq = lane >> 4;
  __shared__ __align__(16) char lds[18432];
  const int row4 = t >> 2, c4 = (t & 3) * 8;

  const bool isK = blockIdx.x < 512;
  if (isK) {
    const int bx = blockIdx.x >> 1, d0 = (blockIdx.x & 1) * 128;
    const int m0 = bx * 64;
    short* Ab = (short*)lds;
    short* Bb = (short*)(lds + 5120);
    short* tile = (short*)lds;
    ffrag acc[4][2] = {};
    u8v pa, pb0, pb1;
    pa  = *(const u8v*)(kin + (size_t)(m0 + row4) * 256 + c4);
    pb0 = *(const u8v*)(Wk + (size_t)(d0 + row4) * 256 + c4);
    pb1 = *(const u8v*)(Wk + (size_t)(d0 + 64 + row4) * 256 + c4);
    *(bfrag*)(Ab + row4 * 40 + c4) = cvtp(pa);
    *(bfrag*)(Bb + row4 * 40 + c4) = cvtp(pb0);
    *(bfrag*)(Bb + (64 + row4) * 40 + c4) = cvtp(pb1);
#pragma unroll 1
    for (int s = 0; s < 8; ++s) {
      __syncthreads();
      if (s < 7) {
        const int k1 = (s + 1) * 32;
        pa  = *(const u8v*)(kin + (size_t)(m0 + row4) * 256 + k1 + c4);
        pb0 = *(const u8v*)(Wk + (size_t)(d0 + row4) * 256 + k1 + c4);
        pb1 = *(const u8v*)(Wk + (size_t)(d0 + 64 + row4) * 256 + k1 + c4);
      }
      bfrag a[4], b[2];
#pragma unroll
      for (int i = 0; i < 4; ++i)
        a[i] = *(const bfrag*)(Ab + (i * 16 + lrow) * 40 + lq * 8);
#pragma unroll
      for (int j = 0; j < 2; ++j)
        b[j] = *(const bfrag*)(Bb + (wid * 32 + j * 16 + lrow) * 40 + lq * 8);
#pragma unroll
      for (int i = 0; i < 4; ++i)
#pragma unroll
        for (int j = 0; j < 2; ++j)
          acc[i][j] = __builtin_amdgcn_mfma_f32_16x16x32_bf16(a[i], b[j], acc[i][j], 0, 0, 0);
      __syncthreads();
      if (s < 7) {
        *(bfrag*)(Ab + row4 * 40 + c4) = cvtp(pa);
        *(bfrag*)(Bb + row4 * 40 + c4) = cvtp(pb0);
        *(bfrag*)(Bb + (64 + row4) * 40 + c4) = cvtp(pb1);
      }
    }
    __syncthreads();
#pragma unroll
    for (int j = 0; j < 2; ++j) {
      int dl = wid * 32 + j * 16 + lrow;
      float bs = bk[d0 + dl];
#pragma unroll
      for (int i = 0; i < 4; ++i)
#pragma unroll
        for (int r = 0; r < 4; ++r)
          tile[(i * 16 + lq * 4 + r) * 136 + dl] = f2bf(acc[i][j][r] + bs);
    }
    __syncthreads();
#pragma unroll
    for (int p = 0; p < 4; ++p) {
      int id2 = p * 256 + t;
      int row = id2 >> 4, c = id2 & 15;
      bfrag v = *(const bfrag*)(tile + row * 136 + c * 8);
      *(bfrag*)(ko + (size_t)(m0 + row) * 256 + d0 + c * 8) = v;
    }
  } else {
    const int t2 = blockIdx.x - 512;
    const int bx = t2 >> 1, d0 = (t2 & 1) * 128;
    const int n0 = bx * 64;
    short* Aw = (short*)lds;
    short* Bv = (short*)(lds + 10240);
    short* tile = (short*)lds;
    ffrag acc[2][4] = {};
    u8v pv, pw0, pw1;
    pw0 = *(const u8v*)(Wv + (size_t)(d0 + row4) * 256 + c4);
    pw1 = *(const u8v*)(Wv + (size_t)(d0 + 64 + row4) * 256 + c4);
    pv  = *(const u8v*)(vin + (size_t)(n0 + row4) * 256 + c4);
    *(bfrag*)(Aw + row4 * 40 + c4) = cvtp(pw0);
    *(bfrag*)(Aw + (64 + row4) * 40 + c4) = cvtp(pw1);
    *(bfrag*)(Bv + row4 * 40 + c4) = cvtp(pv);
#pragma unroll 1
    for (int s = 0; s < 8; ++s) {
      __syncthreads();
      if (s < 7) {
        const int k1 = (s + 1) * 32;
        pw0 = *(const u8v*)(Wv + (size_t)(d0 + row4) * 256 + k1 + c4);
        pw1 = *(const u8v*)(Wv + (size_t)(d0 + 64 + row4) * 256 + k1 + c4);
        pv  = *(const u8v*)(vin + (size_t)(n0 + row4) * 256 + k1 + c4);
      }
      bfrag a[2], b[4];
#pragma unroll
      for (int i = 0; i < 2; ++i)
        a[i] = *(const bfrag*)(Aw + (wid * 32 + i * 16 + lrow) * 40 + lq * 8);
#pragma unroll
      for (int j = 0; j < 4; ++j)
        b[j] = *(const bfrag*)(Bv + (j * 16 + lrow) * 40 + lq * 8);
#pragma unroll
      for (int i = 0; i < 2; ++i)
#pragma unroll
        for (int j = 0; j < 4; ++j)
          acc[i][j] = __builtin_amdgcn_mfma_f32_16x16x32_bf16(a[i], b[j], acc[i][j], 0, 0, 0);
      __syncthreads();
      if (s < 7) {
        *(bfrag*)(Aw + row4 * 40 + c4) = cvtp(pw0);
        *(bfrag*)(Aw + (64 + row4) * 40 + c4) = cvtp(pw1);
        *(bfrag*)(Bv + row4 * 40 + c4) = cvtp(pv);
      }
    }
    __syncthreads();
#pragma unroll
    for (int i = 0; i < 2; ++i)
#pragma unroll
      for (int r = 0; r < 4; ++r) {
        int dl = wid * 32 + i * 16 + lq * 4 + r;
        float bs = bv[d0 + dl];
#pragma unroll
        for (int j = 0; j < 4; ++j)
          tile[dl * 72 + j * 16 + lrow] = f2bf(acc[i][j][r] + bs);
      }
    __syncthreads();
    const int bt = n0 >> 10, sl0 = n0 & 1023;
#pragma unroll
    for (int p = 0; p < 4; ++p) {
      int id2 = p * 256 + t;
      int dl = id2 >> 3, c = id2 & 7;
      bfrag v = *(const bfrag*)(tile + dl * 72 + c * 8);
      *(bfrag*)(vt + (size_t)bt * 262144 + (size_t)(d0 + dl) * 1024 + sl0 + c * 8) = v;
    }
  }
}

// ---- asm-pipelined KV-chunk helpers (compiler-proof prefetch) ----
// ISSUE: fire 8 independent global_load_dwordx4 into a register set.
// WAITP: tied s_waitcnt vmcnt(0) -> consumers data-depend on the wait;
//        sched_barrier stops MFMA hoisting past it (rule #18).
#define ISSUE(kf_, av_, kc1)                                                     \
  do {                                                                           \
    _Pragma("unroll") for (int f_ = 0; f_ < 4; ++f_) {                           \
      const short* pk_ = Kb + (size_t)((kc1) + f_ * 16 + lrow) * 256 + h * 32 + lq * 8; \
      asm volatile("global_load_dwordx4 %0, %1, off" : "=v"(kf_[f_]) : "v"(pk_)); \
    }                                                                            \
    _Pragma("unroll") for (int dj_ = 0; dj_ < 2; ++dj_)                          \
      _Pragma("unroll") for (int b_ = 0; b_ < 2; ++b_) {                         \
        const short* pv_ = Vb + (size_t)(dj_ * 16 + lrow) * 1024 + (kc1) + b_ * 32 + lq * 8; \
        asm volatile("global_load_dwordx4 %0, %1, off" : "=v"(av_[dj_][b_]) : "v"(pv_)); \
      }                                                                          \
  } while (0)

#define WAITP(kf_, av_)                                                          \
  do {                                                                           \
    asm volatile("s_waitcnt vmcnt(0)"                                            \
                 : "+v"(kf_[0]), "+v"(kf_[1]), "+v"(kf_[2]), "+v"(kf_[3]),       \
                   "+v"(av_[0][0]), "+v"(av_[0][1]), "+v"(av_[1][0]), "+v"(av_[1][1]) \
                 :: "memory");                                                   \
    __builtin_amdgcn_sched_barrier(0);                                           \
  } while (0)

#define PCHUNK(kf_, av_, kcv)                                                    \
  do {                                                                           \
    const int kc_ = (kcv);                                                       \
    const ffrag zf_ = {0.f, 0.f, 0.f, 0.f};                                      \
    ffrag st_[2][4];                                                             \
    _Pragma("unroll") for (int g_ = 0; g_ < 2; ++g_)                             \
      _Pragma("unroll") for (int f_ = 0; f_ < 4; ++f_)                           \
        st_[g_][f_] = __builtin_amdgcn_mfma_f32_16x16x32_bf16(kf_[f_], qf[g_], zf_, 0, 0, 0); \
    const bool fullc_ = (kc_ + 64 <= L);                                         \
    _Pragma("unroll") for (int g_ = 0; g_ < 2; ++g_) {                           \
      float p_[4][4];                                                            \
      if (fullc_) {                                                              \
        _Pragma("unroll") for (int f_ = 0; f_ < 4; ++f_)                         \
          _Pragma("unroll") for (int r_ = 0; r_ < 4; ++r_) {                     \
            p_[f_][r_] = __builtin_amdgcn_exp2f(st_[g_][f_][r_]);                \
            l_loc[g_] += p_[f_][r_];                                             \
          }                                                                      \
      } else {                                                                   \
        _Pragma("unroll") for (int f_ = 0; f_ < 4; ++f_)                         \
          _Pragma("unroll") for (int r_ = 0; r_ < 4; ++r_) {                     \
            int kr_ = kc_ + f_ * 16 + lq * 4 + r_;                               \
            float pvx_ = (kr_ < L) ? __builtin_amdgcn_exp2f(st_[g_][f_][r_]) : 0.f; \
            p_[f_][r_] = pvx_;                                                   \
            l_loc[g_] += pvx_;                                                   \
          }                                                                      \
      }                                                                          \
      _Pragma("unroll") for (int f_ = 0; f_ < 4; ++f_) {                         \
        u2v w_;                                                                  \
        w_[0] = packbf(p_[f_][0], p_[f_][1]);                                    \
        w_[1] = packbf(p_[f_][2], p_[f_][3]);                                    \
        *(u2v*)(ptg + lrow * 36 + 8 * f_ + 2 * lq) = w_;                         \
      }                                                                          \
      _Pragma("unroll") for (int b_ = 0; b_ < 2; ++b_) {                         \
        u4v pv4_ = *(const u4v*)(ptg + lrow * 36 + 16 * b_ + 4 * lq);            \
        union { u4v u; bfrag bf; } pt_; pt_.u = pv4_;                            \
        _Pragma("unroll") for (int dj_ = 0; dj_ < 2; ++dj_)                      \
          o[g_][dj_] = __builtin_amdgcn_mfma_f32_16x16x32_bf16(av_[dj_][b_], pt_.bf, o[g_][dj_], 0, 0, 0); \
      }                                                                          \
    }                                                                            \
  } while (0)

// ---- fused attn v5: v3 structure + asm-pipelined phase 2 ----
// grid 512 x 512 thr; 32 q-rows/block; 1 head/wave, 2 g-streams.
__global__ __launch_bounds__(512, 2) void attn_fused(
    const float* __restrict__ query, const float* __restrict__ Wq,
    const float* __restrict__ bq, const float* __restrict__ Wo,
    const float* __restrict__ bo, const short* __restrict__ K,
    const short* __restrict__ Vt, const int* __restrict__ mask,
    float* __restrict__ out) {
  const int lane = threadIdx.x & 63, wid = threadIdx.x >> 6;  // wid = head
  const int lrow = lane & 15, lq = lane >> 4;
  const int id = blockIdx.x;
  const int bt = (id + (id >> 8)) & 15;  // CU-pair gets different L
  const int qt = id >> 4;
  const int q0 = qt * 32;
  const int L = mask[bt];
  const int h = wid;
  const bool isLast = (qt == 31);
  const int nvalid = min(max(L - q0, 0), 32);

  if (nvalid <= 0 && !isLast) return;  // rows covered by qt=31 broadcast
  const bool colsumOnly = isLast && (nvalid <= 0);

  __shared__ __align__(16) short qx[32 * 264];              // Q tile -> X tile
  __shared__ __align__(16) unsigned int ptbuf[8][16 * 36];  // per-wave P^T
  unsigned int* ptg = &ptbuf[wid][0];
  float* vbuf = (float*)&ptbuf[0][0];                       // broadcast vector (D-mode)

  const short* Vb = Vt + ((size_t)bt * 8 + h) * 32768;  // [32][1024]
  float l_i[2];
  ffrag o[2][2] = {};  // o[g][dj]

  if (!colsumOnly) {
    // ---- phase 1: Q projection into LDS, pre-scaled by EXPC; slab prefetch ----
    {
      const int n0 = h * 32;
      const float* X = query + ((size_t)bt * 1024 + q0) * 256;
      ffrag acc[2][2] = {};
      u8v xa[2], wb[2], xa_n[2], wb_n[2];
#pragma unroll
      for (int i = 0; i < 2; ++i)
        xa[i] = *(const u8v*)(X + (size_t)(i * 16 + lrow) * 256 + lq * 8);
#pragma unroll
      for (int j = 0; j < 2; ++j)
        wb[j] = *(const u8v*)(Wq + (size_t)(n0 + j * 16 + lrow) * 256 + lq * 8);
#pragma unroll 1
      for (int tt = 0; tt < 8; ++tt) {
        if (tt < 7) {
          const int kk = (tt + 1) * 32;
#pragma unroll
          for (int i = 0; i < 2; ++i)
            xa_n[i] = *(const u8v*)(X + (size_t)(i * 16 + lrow) * 256 + kk + lq * 8);
#pragma unroll
          for (int j = 0; j < 2; ++j)
            wb_n[j] = *(const u8v*)(Wq + (size_t)(n0 + j * 16 + lrow) * 256 + kk + lq * 8);
        }
        bfrag a[2], b[2];
#pragma unroll
        for (int i = 0; i < 2; ++i) a[i] = cvtp(xa[i]);
#pragma unroll
        for (int j = 0; j < 2; ++j) b[j] = cvtp(wb[j]);
#pragma unroll
        for (int i = 0; i < 2; ++i)
#pragma unroll
          for (int j = 0; j < 2; ++j)
            acc[i][j] = __builtin_amdgcn_mfma_f32_16x16x32_bf16(a[i], b[j], acc[i][j], 0, 0, 0);
#pragma unroll
        for (int i = 0; i < 2; ++i) xa[i] = xa_n[i];
#pragma unroll
        for (int j = 0; j < 2; ++j) wb[j] = wb_n[j];
      }
#pragma unroll
      for (int j = 0; j < 2; ++j) {
        int d = n0 + j * 16 + lrow;
        float bs = bq[d];
#pragma unroll
        for (int i = 0; i < 2; ++i)
#pragma unroll
          for (int r = 0; r < 4; ++r)
            qx[(i * 16 + lq * 4 + r) * 264 + d] = f2bf((acc[i][j][r] + bs) * EXPC);
      }
    }
    // no barrier: wave reads only its own columns until phase 3

    // ---- phase 2: S^T = K·Q^T with asm double-set pipeline ----
    const short* Kb = K + (size_t)bt * 262144;  // [1024][256]
    bfrag qf[2];
#pragma unroll
    for (int g = 0; g < 2; ++g)
      qf[g] = *(const bfrag*)(qx + (g * 16 + lrow) * 264 + h * 32 + lq * 8);

    const int nchunk = (L + 63) >> 6;
    float l_loc[2] = {0.f, 0.f};
    bfrag kfA[4] = {}, avA[2][2] = {}, kfB[4] = {}, avB[2][2] = {};

    int c = 0;
    ISSUE(kfA, avA, 0);
    for (;;) {
      WAITP(kfA, avA);
      if (c + 1 < nchunk) ISSUE(kfB, avB, (c + 1) * 64);
      PCHUNK(kfA, avA, c * 64);
      if (++c >= nchunk) break;
      WAITP(kfB, avB);
      if (c + 1 < nchunk) ISSUE(kfA, avA, (c + 1) * 64);
      PCHUNK(kfB, avB, c * 64);
      if (++c >= nchunk) break;
    }

    // row-sum l across the 4 lane-quads
#pragma unroll
    for (int g = 0; g < 2; ++g) {
      float rs = l_loc[g];
      rs += __shfl_xor(rs, 16);
      rs += __shfl_xor(rs, 32);
      l_i[g] = rs;
    }
  } else {
#pragma unroll
    for (int g = 0; g < 2; ++g) l_i[g] = 1024.f;
  }

  // ---- tail (ONLY block qt=31): invalid rows -> colsum(V) via indicator MFMA ----
  if (isLast && nvalid < 32) {
#pragma unroll
    for (int g = 0; g < 2; ++g) {
      bool inv = (g * 16 + lrow) >= nvalid;
      if (inv) {
        l_i[g] = 1024.f;
#pragma unroll
        for (int dj = 0; dj < 2; ++dj)
#pragma unroll
          for (int r = 0; r < 4; ++r) o[g][dj][r] = 0.f;
      }
    }
    bfrag ind[2];
#pragma unroll
    for (int g = 0; g < 2; ++g) {
      short iv = ((g * 16 + lrow) >= nvalid) ? (short)0x3F80 : (short)0;
#pragma unroll
      for (int j = 0; j < 8; ++j) ind[g][j] = iv;
    }
    const bool g0 = (nvalid < 16);
#pragma unroll 2
    for (int kc = 0; kc < 1024; kc += 64) {
#pragma unroll
      for (int dj = 0; dj < 2; ++dj)
#pragma unroll
        for (int b = 0; b < 2; ++b) {
          bfrag av = *(const bfrag*)(Vb + (size_t)(dj * 16 + lrow) * 1024 + kc + b * 32 + lq * 8);
          if (g0)
            o[0][dj] = __builtin_amdgcn_mfma_f32_16x16x32_bf16(av, ind[0], o[0][dj], 0, 0, 0);
          o[1][dj] = __builtin_amdgcn_mfma_f32_16x16x32_bf16(av, ind[1], o[1][dj], 0, 0, 0);
        }
    }
  }

  // write x into qx: lane holds qrow = g*16+lrow, d = dj*16 + 4*lq + r
#pragma unroll
  for (int g = 0; g < 2; ++g) {
    float rcp = 1.0f / l_i[g];
#pragma unroll
    for (int dj = 0; dj < 2; ++dj) {
      u2v w;
      w[0] = packbf(o[g][dj][0] * rcp, o[g][dj][1] * rcp);
      w[1] = packbf(o[g][dj][2] * rcp, o[g][dj][3] * rcp);
      short* dst = qx + (g * 16 + lrow) * 264 + h * 32 + dj * 16 + lq * 4;
      *(u2v*)dst = w;
    }
  }
  __syncthreads();

  // ---- phase 3: output projection; Wo prefetched one slab ahead ----
  {
    const int n0 = h * 32;
    ffrag acc[2][2] = {};
    u8v wb[2], wb_n[2];
#pragma unroll
    for (int j = 0; j < 2; ++j)
      wb[j] = *(const u8v*)(Wo + (size_t)(n0 + j * 16 + lrow) * 256 + lq * 8);
#pragma unroll 1
    for (int tt = 0; tt < 8; ++tt) {
      const int k0 = tt * 32;
      if (tt < 7) {
#pragma unroll
        for (int j = 0; j < 2; ++j)
          wb_n[j] = *(const u8v*)(Wo + (size_t)(n0 + j * 16 + lrow) * 256 + k0 + 32 + lq * 8);
      }
      bfrag a[2], b[2];
#pragma unroll
      for (int i = 0; i < 2; ++i)
        a[i] = *(const bfrag*)(qx + (i * 16 + lrow) * 264 + k0 + lq * 8);
#pragma unroll
      for (int j = 0; j < 2; ++j) b[j] = cvtp(wb[j]);
#pragma unroll
      for (int i = 0; i < 2; ++i)
#pragma unroll
        for (int j = 0; j < 2; ++j)
          acc[i][j] = __builtin_amdgcn_mfma_f32_16x16x32_bf16(a[i], b[j], acc[i][j], 0, 0, 0);
#pragma unroll
      for (int j = 0; j < 2; ++j) wb[j] = wb_n[j];
    }

    if (!colsumOnly) {
      // normal store; partial blocks store only rows < L (block 31 stores all)
#pragma unroll
      for (int j = 0; j < 2; ++j) {
        int d = n0 + j * 16 + lrow;
        float bs = bo[d];
#pragma unroll
        for (int i = 0; i < 2; ++i)
#pragma unroll
          for (int r = 0; r < 4; ++r) {
            int qr = q0 + i * 16 + lq * 4 + r;
            if (qr < L || isLast)
              out[((size_t)bt * 1024 + qr) * 256 + d] = acc[i][j][r] + bs;
          }
      }
    } else {
      // D-mode: all rows identical -> build 256-vector in LDS, broadcast rows L..1023
      if (lq == 0) {
#pragma unroll
        for (int j = 0; j < 2; ++j) {
          int d = n0 + j * 16 + lrow;
          vbuf[d] = acc[0][j][0] + bo[d];
        }
      }
      __syncthreads();
      const int d = threadIdx.x & 255;
      const float vv = vbuf[d];
      float* ob = out + (size_t)bt * 1024 * 256 + d;
#pragma unroll 1
      for (int row = L + (threadIdx.x >> 8); row < 1024; row += 2)
        ob[(size_t)row * 256] = vv;
    }
  }
}

extern "C" void kernel_launch(void* const* d_in, const int* in_sizes, int n_in,
                              void* d_out, int out_size, void* d_ws, size_t ws_size,
                              hipStream_t stream) {
  const float* query = (const float*)d_in[0];
  const float* key   = (const float*)d_in[1];
  const float* value = (const float*)d_in[2];
  const int*   mask  = (const int*)d_in[3];
  const float* Wq = (const float*)d_in[4];
  const float* bq = (const float*)d_in[5];
  const float* Wk = (const float*)d_in[6];
  const float* bk = (const float*)d_in[7];
  const float* Wv = (const float*)d_in[8];
  const float* bv = (const float*)d_in[9];
  const float* Wo = (const float*)d_in[10];
  const float* bo = (const float*)d_in[11];
  float* out = (float*)d_out;

  // workspace: K bf16 (8 MB) + Vt bf16 (8 MB) = 16,777,216 bytes exactly
  short* k_ws  = (short*)d_ws;
  short* vt_ws = k_ws + 4194304;

  proj_kv<<<dim3(1024), 256, 0, stream>>>(key, Wk, bk, value, Wv, bv, k_ws, vt_ws);
  attn_fused<<<dim3(512), 512, 0, stream>>>(query, Wq, bq, Wo, bo,
                                            k_ws, vt_ws, mask, out);
}